// Round 8
// baseline (4644.958 us; speedup 1.0000x reference)
//
#include <hip/hip_runtime.h>
#include <stdint.h>

// ---------------------------------------------------------------------------
// TreeLSTMParser: N=2048 nodes/timesteps, D_IN=H=768, OUT=128.
// Tree: complete binary tree, parent(i)=(i-1)/2; level L = [2^(10-L),2^(11-L))
// for L=1..10, level 0 = leaves [1024,2048), level 11 = {0}.
//
// Inputs fp32 (detector-confirmed r3).  All tensors canonicalized to bf16.
//
// v12: seq_lstm internal-chain restructure (single-wave gate pipeline).
// r13 model: step 3634cyc = detect ~2800 (structural agent-scope latency,
// v10) + internal ~800 (B1 + 12 chained MFMA + B2 + part[] + 32-thread gate
// serialization).  v12: 8 waves x 512thr; wave wv owns 4 j, computes ALL 4
// gates full-K (16 B-rows = 4 gates x 4 j), 24 MFMA in 4 independent acc
// chains; gate gather = in-wave shfl; lanes 0/2 publish packed u64; ONE
// barrier/step.  Comm protocol byte-identical to v10/v11.
// ---------------------------------------------------------------------------

typedef __bf16 bf16x8 __attribute__((ext_vector_type(8)));
typedef float  f32x4  __attribute__((ext_vector_type(4)));
typedef unsigned long long u64;

__device__ __forceinline__ float bf2f(uint16_t v) {
    return __uint_as_float(((uint32_t)v) << 16);
}
__device__ __forceinline__ uint16_t f2bf(float f) {
    uint32_t u = __float_as_uint(f);
    uint32_t r = (u + 0x7fffu + ((u >> 16) & 1u)) >> 16;
    return (uint16_t)r;
}
__device__ __forceinline__ float sigf(float x) { return 1.0f / (1.0f + __expf(-x)); }
__device__ __forceinline__ float tanh_f(float x) {
    x = fminf(fmaxf(x, -15.0f), 15.0f);
    float e = __expf(2.0f * x);
    return (e - 1.0f) / (e + 1.0f);
}

// ---------------------------------------------------------------------------
// K0a: dtype detector (fp32 read as bf16 halfwords shows exponent==0xFF).
// ---------------------------------------------------------------------------
__global__ __launch_bounds__(256)
void detect_mode(const uint16_t* __restrict__ p, int* __restrict__ mode)
{
    int i = blockIdx.x * 256 + threadIdx.x;
    uint16_t v = p[i];
    bool bad = ((v >> 7) & 0xFF) == 0xFF;
    if (__ballot(bad) != 0ull) {
        if ((threadIdx.x & 63) == 0) atomicOr(mode, 1);
    }
}

// ---------------------------------------------------------------------------
// K0b: canonicalize all tensors to bf16 (copy or downcast per mode).
// ---------------------------------------------------------------------------
struct ConvArgs {
    const void* src[14];
    void*       dst[14];
    int         n[14];
};

__global__ __launch_bounds__(256)
void conv_canon(ConvArgs a, const int* __restrict__ mode)
{
    int t = blockIdx.y;
    int n = a.n[t];
    int i = (blockIdx.x * 256 + threadIdx.x) * 8;
    if (i >= n) return;
    uint16_t* d = (uint16_t*)a.dst[t] + i;
    if (*mode) {
        const float* s = (const float*)a.src[t] + i;
        float4 v0 = reinterpret_cast<const float4*>(s)[0];
        float4 v1 = reinterpret_cast<const float4*>(s)[1];
        d[0] = f2bf(v0.x); d[1] = f2bf(v0.y); d[2] = f2bf(v0.z); d[3] = f2bf(v0.w);
        d[4] = f2bf(v1.x); d[5] = f2bf(v1.y); d[6] = f2bf(v1.z); d[7] = f2bf(v1.w);
    } else {
        *reinterpret_cast<uint4*>(d) =
            *reinterpret_cast<const uint4*>((const uint16_t*)a.src[t] + i);
    }
}

// ---------------------------------------------------------------------------
// K1: fused projection GEMM.  C(2048 x 6144) = A @ W^T + bias, K=768.
// seq region written PERMUTED for 32-wide wg ownership (24 wgs x 32 j,
// v4 mapping): idx = (j>>5)*128 + g*32 + (j&31)
// ---------------------------------------------------------------------------
__global__ __launch_bounds__(256)
void gemm_pre(const uint16_t* __restrict__ treeF, const uint16_t* __restrict__ featF,
              const uint16_t* __restrict__ W_iou, const uint16_t* __restrict__ b_iou,
              const uint16_t* __restrict__ W_f,   const uint16_t* __restrict__ b_f,
              const uint16_t* __restrict__ W_ih,  const uint16_t* __restrict__ b_ih,
              const uint16_t* __restrict__ b_hh,
              uint16_t* __restrict__ x_iou, uint16_t* __restrict__ x_f,
              uint16_t* __restrict__ seq_pre)
{
    int lane = threadIdx.x & 63;
    int wave = threadIdx.x >> 6;
    int colTile = blockIdx.x * 4 + wave;     // 0..383
    int row0 = blockIdx.y * 16;              // 0..2032
    int cl = lane & 15, quad = lane >> 4;
    int colg = colTile * 16;

    const uint16_t* A; const uint16_t* W; int wrow;
    if (colTile < 144)      { A = treeF; W = W_iou; wrow = colg; }
    else if (colTile < 192) { A = treeF; W = W_f;   wrow = colg - 2304; }
    else                    { A = featF; W = W_ih;  wrow = colg - 3072; }

    const uint16_t* arow = A + (size_t)(row0 + cl) * 768 + quad * 8;
    const uint16_t* brow = W + (size_t)(wrow + cl) * 768 + quad * 8;

    f32x4 acc = {0.f, 0.f, 0.f, 0.f};
    for (int k = 0; k < 768; k += 32) {
        bf16x8 a = *reinterpret_cast<const bf16x8*>(arow + k);
        bf16x8 b = *reinterpret_cast<const bf16x8*>(brow + k);
        acc = __builtin_amdgcn_mfma_f32_16x16x32_bf16(a, b, acc, 0, 0, 0);
    }

    // C/D layout: col = lane&15, row = quad*4 + reg   [m89-verified]
    int outcol = colg + cl;
    float bias; uint16_t* dst; int ldc; int ccol;
    if (colTile < 144)      { bias = bf2f(b_iou[outcol]); dst = x_iou; ldc = 2304; ccol = outcol; }
    else if (colTile < 192) { int c = outcol - 2304; bias = bf2f(b_f[c]); dst = x_f; ldc = 768;  ccol = c; }
    else {
        int c = outcol - 3072;               // c = g*768 + j
        int g = c / 768, j = c - g * 768;
        bias = bf2f(b_ih[c]) + bf2f(b_hh[c]);
        dst = seq_pre; ldc = 3072;
        ccol = (j >> 5) * 128 + g * 32 + (j & 31);   // v4 permutation
    }
    for (int r = 0; r < 4; ++r) {
        int row = row0 + quad * 4 + r;
        dst[(size_t)row * ldc + ccol] = f2bf(acc[r] + bias);
    }
}

// ---------------------------------------------------------------------------
// K2a v2: per-level dot products (tree), MFMA.
// GEMM1: x_iou[p][j] += dot(U_iou[j], h[2p+1]+h[2p+2]), p-tile 16 x j-tile 16,
//        hsum via two chained MFMAs.  144 col tiles.
// GEMM2: fdot[c][j] = x_f[parent(c)][j] + dot(U_f[j], h[c]).  48 col tiles.
// hb row 2048 = zeros (node 1023 phantom child).  Row-clamp + store-guard
// handle partial tiles (m<16).
// ---------------------------------------------------------------------------
__global__ __launch_bounds__(256)
void tree_dots_mfma(int s, int m,
                    const uint16_t* __restrict__ U_iou, const uint16_t* __restrict__ U_f,
                    const uint16_t* __restrict__ x_f,
                    uint16_t* __restrict__ x_iou, uint16_t* __restrict__ fdot,
                    const uint16_t* __restrict__ hb)
{
    int lane = threadIdx.x & 63;
    int wave = threadIdx.x >> 6;
    int cl = lane & 15, quad = lane >> 4;
    int mt1 = (m + 15) >> 4;
    int mt2 = (2 * m + 15) >> 4;
    int t1 = mt1 * 144;
    int tile = blockIdx.x * 4 + wave;
    if (tile >= t1 + mt2 * 48) return;

    if (tile < t1) {
        int rt = tile / 144, ct = tile - rt * 144;
        int pl = rt * 16 + cl; if (pl > m - 1) pl = m - 1;   // A-row clamp
        int p = s + pl;
        const uint16_t* a1 = hb + (size_t)(2 * p + 1) * 768 + quad * 8;
        const uint16_t* a2 = hb + (size_t)(2 * p + 2) * 768 + quad * 8;
        const uint16_t* brow = U_iou + (size_t)(ct * 16 + cl) * 768 + quad * 8;
        f32x4 acc = {0.f, 0.f, 0.f, 0.f};
        for (int k = 0; k < 768; k += 32) {
            bf16x8 b = *reinterpret_cast<const bf16x8*>(brow + k);
            acc = __builtin_amdgcn_mfma_f32_16x16x32_bf16(
                      *reinterpret_cast<const bf16x8*>(a1 + k), b, acc, 0, 0, 0);
            acc = __builtin_amdgcn_mfma_f32_16x16x32_bf16(
                      *reinterpret_cast<const bf16x8*>(a2 + k), b, acc, 0, 0, 0);
        }
        int outcol = ct * 16 + cl;
        #pragma unroll
        for (int r = 0; r < 4; ++r) {
            int prow = rt * 16 + quad * 4 + r;
            if (prow < m) {
                size_t off = (size_t)(s + prow) * 2304 + outcol;
                x_iou[off] = f2bf(bf2f(x_iou[off]) + acc[r]);
            }
        }
    } else {
        int t2i = tile - t1;
        int rt = t2i / 48, ct = t2i - rt * 48;
        int c0 = 2 * s + 1;
        int rl = rt * 16 + cl; if (rl > 2 * m - 1) rl = 2 * m - 1;  // clamp
        const uint16_t* a = hb + (size_t)(c0 + rl) * 768 + quad * 8;
        const uint16_t* brow = U_f + (size_t)(ct * 16 + cl) * 768 + quad * 8;
        f32x4 acc = {0.f, 0.f, 0.f, 0.f};
        for (int k = 0; k < 768; k += 32) {
            acc = __builtin_amdgcn_mfma_f32_16x16x32_bf16(
                      *reinterpret_cast<const bf16x8*>(a + k),
                      *reinterpret_cast<const bf16x8*>(brow + k), acc, 0, 0, 0);
        }
        int outcol = ct * 16 + cl;
        #pragma unroll
        for (int r = 0; r < 4; ++r) {
            int rr = rt * 16 + quad * 4 + r;
            int c = c0 + rr;
            if (rr < 2 * m && c < 2048) {
                int p = (c - 1) >> 1;
                fdot[(size_t)c * 768 + outcol] =
                    f2bf(bf2f(x_f[(size_t)p * 768 + outcol]) + acc[r]);
            }
        }
    }
}

// ---------------------------------------------------------------------------
// K2b: per-level combine (tree).  Writes bf16 h (tree_hb) + fp32 c.
// ---------------------------------------------------------------------------
__global__ __launch_bounds__(256)
void tree_combine(int s, int m, const uint16_t* __restrict__ x_iou,
                  const uint16_t* __restrict__ fdot,
                  uint16_t* __restrict__ tree_hb, float* __restrict__ tree_c)
{
    int id = blockIdx.x * 256 + threadIdx.x;
    int pl = id / 768;
    int j = id - pl * 768;
    int p = s + pl;
    const uint16_t* iou = x_iou + (size_t)p * 2304;
    float iv = sigf(bf2f(iou[j]));
    float ov = sigf(bf2f(iou[768 + j]));
    float uv = tanh_f(bf2f(iou[1536 + j]));
    float csum = 0.f;
    int c1 = 2 * p + 1, c2 = 2 * p + 2;
    if (c1 < 2048) csum += sigf(bf2f(fdot[(size_t)c1 * 768 + j])) * tree_c[(size_t)c1 * 768 + j];
    if (c2 < 2048) csum += sigf(bf2f(fdot[(size_t)c2 * 768 + j])) * tree_c[(size_t)c2 * 768 + j];
    float c = iv * uv + csum;
    tree_c[(size_t)p * 768 + j] = c;
    tree_hb[(size_t)p * 768 + j] = f2bf(ov * tanh_f(c));
}

// ---------------------------------------------------------------------------
// K3 v12: persistent sequential LSTM.  Launch 256 wgs x 512 thr; 24 workers
// claim slots on ONE XCD (v10 protocol).  Single-wave gate pipeline:
//
// Wave wv (0..7) owns j = j0..j0+3 (j0 = bid*32 + wv*4).  Its 16 MFMA
// B-rows = W_hh rows {g*768 + j0 + jj : g=cl>>2, jj=cl&3}.  Full K=768 =
// 24 MFMA (4 independent acc chains of 6).  A-operand = h broadcast (lane's
// quad reads chunk quad*8 — identical rows) => every lane's acc[0] = gate
// value for its (g,jj).  + pre, then in-wave shfl gather of the 4 gates,
// replicated gate math, lanes 0/2 publish packed u64, lanes 0..3 write hsb.
// ONE barrier per step (B1).  Parity LDS + tag chain as v9/v10.
// ---------------------------------------------------------------------------
#define SEQ_WGS 24
#define SEQ_LAUNCH 256
__global__ __launch_bounds__(512)
void seq_lstm(const uint16_t* __restrict__ W_hh, const uint16_t* __restrict__ seq_pre,
              uint16_t* __restrict__ hsb, u64* __restrict__ h_comm, int* __restrict__ ctl)
{
    __shared__ uint16_t hb16[2][768];   // bf16 h, parity-buffered
    __shared__ int      s_slot;

    int tid = threadIdx.x;

    // ---- placement claim: prefer one XCD for all workers ----
    int xcc;
    asm("s_getreg_b32 %0, hwreg(HW_REG_XCC_ID)" : "=s"(xcc));
    if (tid == 0) {
        int tgt = atomicCAS(&ctl[1], -1, xcc);   // first claimer sets target
        if (tgt == -1) tgt = xcc;
        int slot;
        if (xcc == tgt) {
            slot = atomicAdd(&ctl[0], 1);
        } else {
            int it = 0;
            for (;;) {
                int tk = __hip_atomic_load(&ctl[0], __ATOMIC_RELAXED,
                                           __HIP_MEMORY_SCOPE_AGENT);
                if (tk >= SEQ_WGS) { slot = 0x7fffffff; break; }  // filled: exit
                if (++it > 2000) { slot = atomicAdd(&ctl[0], 1); break; }  // fallback
                __builtin_amdgcn_s_sleep(8);
            }
        }
        s_slot = slot;
    }
    __syncthreads();
    int bid = s_slot;               // worker slot 0..23
    if (bid >= SEQ_WGS) return;     // non-worker wgs exit whole

    int lane = tid & 63;
    int wv   = tid >> 6;            // wave 0..7, owns 4 j
    int cl   = lane & 15;
    int quad = lane >> 4;
    int g    = cl >> 2;             // gate of this lane's W row
    int jj   = lane & 3;            // j within the wave's group of 4
    int j0   = bid * 32 + wv * 4;
    int rglob = g * 768 + j0 + (cl & 3);        // W_hh row for this lane
    int preOff = bid * 128 + g * 32 + (wv * 4 + (cl & 3));  // v4 permutation

    // weight fragments: lane holds W[rglob][ks*32 + quad*8 ..+8), ks=0..23
    bf16x8 wq[24];
    {
        const uint16_t* src = W_hh + (size_t)rglob * 768 + quad * 8;
        #pragma unroll
        for (int i = 0; i < 24; ++i)
            wq[i] = *reinterpret_cast<const bf16x8*>(src + i * 32);
    }

    float cstate = 0.f;             // replicated: this lane's j = j0 + jj

    for (int t = 0; t < 2048; ++t) {
        float pre = bf2f(seq_pre[(size_t)t * 3072 + preOff]);  // own-lane prefetch
        uint16_t* hb = hb16[t & 1];

        if (t > 0) {
            if (tid < 384) {
                const u64* hw = h_comm + (size_t)((t - 1) & 1) * 384 + tid;
                u64 a;
                int guard = 0;
                for (;;) {
                    a = __hip_atomic_load(hw, __ATOMIC_RELAXED,
                                          __HIP_MEMORY_SCOPE_AGENT);
                    if ((uint32_t)(a >> 32) >= (uint32_t)t) break;
                    if (++guard > (1 << 22)) break;      // hang bailout
                    __builtin_amdgcn_s_sleep(1);
                }
                hb[2 * tid]     = (uint16_t)a;           // bf16 payload lo
                hb[2 * tid + 1] = (uint16_t)(a >> 16);   // bf16 payload hi
            }
        } else {
            if (tid < 384) { hb[2 * tid] = 0; hb[2 * tid + 1] = 0; }
        }
        __syncthreads();   // B1 — the only barrier per step

        // full-K matvec: 24 MFMA, 4 independent acc chains.
        // A = h broadcast (quad reads chunk quad*8; all 16 rows identical)
        const uint16_t* hbase = hb + quad * 8;
        f32x4 a0 = {0.f,0.f,0.f,0.f}, a1 = {0.f,0.f,0.f,0.f};
        f32x4 a2 = {0.f,0.f,0.f,0.f}, a3 = {0.f,0.f,0.f,0.f};
        #pragma unroll
        for (int ks = 0; ks < 24; ks += 4) {
            a0 = __builtin_amdgcn_mfma_f32_16x16x32_bf16(
                     *reinterpret_cast<const bf16x8*>(hbase + (ks + 0) * 32), wq[ks + 0], a0, 0, 0, 0);
            a1 = __builtin_amdgcn_mfma_f32_16x16x32_bf16(
                     *reinterpret_cast<const bf16x8*>(hbase + (ks + 1) * 32), wq[ks + 1], a1, 0, 0, 0);
            a2 = __builtin_amdgcn_mfma_f32_16x16x32_bf16(
                     *reinterpret_cast<const bf16x8*>(hbase + (ks + 2) * 32), wq[ks + 2], a2, 0, 0, 0);
            a3 = __builtin_amdgcn_mfma_f32_16x16x32_bf16(
                     *reinterpret_cast<const bf16x8*>(hbase + (ks + 3) * 32), wq[ks + 3], a3, 0, 0, 0);
        }
        float gate = (a0[0] + a1[0]) + (a2[0] + a3[0]) + pre;

        // in-wave gather: gate for (g', jj) lives at lane g'*4 + jj (quad 0)
        float gi = __shfl(gate, jj);
        float gf = __shfl(gate, 4 + jj);
        float gg = __shfl(gate, 8 + jj);
        float go = __shfl(gate, 12 + jj);

        float iv = sigf(gi), fv = sigf(gf), gv = tanh_f(gg), ov = sigf(go);
        cstate = fv * cstate + iv * gv;       // replicated per lane (j = j0+jj)
        float hv = ov * tanh_f(cstate);

        // publish: pack 2 j per u64; lanes 0 (jj=0) and 2 (jj=2) store
        uint32_t hvb  = (uint32_t)f2bf(hv);
        uint32_t hvhi = __shfl(hvb, jj | 1);  // odd partner's payload
        if (lane == 0 || lane == 2) {
            int wdx = bid * 16 + wv * 2 + (jj >> 1);
            u64 wd = ((u64)(uint32_t)(t + 1) << 32)
                   | ((u64)hvhi << 16) | (u64)hvb;
            __hip_atomic_store(h_comm + (size_t)(t & 1) * 384 + wdx, wd,
                               __ATOMIC_RELAXED, __HIP_MEMORY_SCOPE_AGENT);
        }
        if (lane < 4)
            hsb[(size_t)t * 768 + j0 + jj] = (uint16_t)hvb;   // off critical path
        // no trailing barrier: hb16 parity + barrier chain protect reuse
    }
}

// ---------------------------------------------------------------------------
// K4 v2: classifier via MFMA.  logits[n][o] = b_cls[o] +
//   dot(W_cls[o][0:768], tree_hb[n]) + dot(W_cls[o][768:1536], hs_b[n]).
// 128 row tiles x 8 col tiles = 1024 tiles, 4 waves/block -> 256 blocks.
// ---------------------------------------------------------------------------
__global__ __launch_bounds__(256)
void cls_mfma(const uint16_t* __restrict__ hbT, const uint16_t* __restrict__ hsb,
              const uint16_t* __restrict__ W_cls, const uint16_t* __restrict__ b_cls,
              float* __restrict__ logits)
{
    int lane = threadIdx.x & 63;
    int wave = threadIdx.x >> 6;
    int cl = lane & 15, quad = lane >> 4;
    int tile = blockIdx.x * 4 + wave;    // 0..1023
    int rt = tile >> 3, ct = tile & 7;
    const uint16_t* a1 = hbT + (size_t)(rt * 16 + cl) * 768 + quad * 8;
    const uint16_t* a2 = hsb + (size_t)(rt * 16 + cl) * 768 + quad * 8;
    const uint16_t* brow = W_cls + (size_t)(ct * 16 + cl) * 1536 + quad * 8;
    f32x4 acc = {0.f, 0.f, 0.f, 0.f};
    for (int k = 0; k < 768; k += 32) {
        acc = __builtin_amdgcn_mfma_f32_16x16x32_bf16(
                  *reinterpret_cast<const bf16x8*>(a1 + k),
                  *reinterpret_cast<const bf16x8*>(brow + k), acc, 0, 0, 0);
        acc = __builtin_amdgcn_mfma_f32_16x16x32_bf16(
                  *reinterpret_cast<const bf16x8*>(a2 + k),
                  *reinterpret_cast<const bf16x8*>(brow + 768 + k), acc, 0, 0, 0);
    }
    int outcol = ct * 16 + cl;
    float bias = bf2f(b_cls[outcol]);
    #pragma unroll
    for (int r = 0; r < 4; ++r) {
        int n = rt * 16 + quad * 4 + r;
        logits[(size_t)n * 128 + outcol] = acc[r] + bias;
    }
}

// ---------------------------------------------------------------------------
// K5: log_softmax over axis=0 per class column.  Output dtype per mode.
// ---------------------------------------------------------------------------
__global__ __launch_bounds__(256)
void col_softmax(const float* __restrict__ logits, void* __restrict__ out,
                 const int* __restrict__ mode)
{
    __shared__ float sred[256];
    int o = blockIdx.x, tid = threadIdx.x;
    float v[8];
    float mx = -1e30f;
    #pragma unroll
    for (int i = 0; i < 8; ++i) {
        v[i] = logits[(size_t)(i * 256 + tid) * 128 + o];
        mx = fmaxf(mx, v[i]);
    }
    sred[tid] = mx; __syncthreads();
    for (int s2 = 128; s2 > 0; s2 >>= 1) {
        if (tid < s2) sred[tid] = fmaxf(sred[tid], sred[tid + s2]);
        __syncthreads();
    }
    float M = sred[0]; __syncthreads();
    float sm = 0.f;
    #pragma unroll
    for (int i = 0; i < 8; ++i) sm += __expf(v[i] - M);
    sred[tid] = sm; __syncthreads();
    for (int s2 = 128; s2 > 0; s2 >>= 1) {
        if (tid < s2) sred[tid] += sred[tid + s2];
        __syncthreads();
    }
    float lse = M + logf(sred[0]);
    bool fp32 = (*mode != 0);
    #pragma unroll
    for (int i = 0; i < 8; ++i) {
        size_t idx = (size_t)(i * 256 + tid) * 128 + o;
        float val = v[i] - lse;
        if (fp32) ((float*)out)[idx] = val;
        else      ((uint16_t*)out)[idx] = f2bf(val);
    }
}

// ---------------------------------------------------------------------------
extern "C" void kernel_launch(void* const* d_in, const int* in_sizes, int n_in,
                              void* d_out, int out_size, void* d_ws, size_t ws_size,
                              hipStream_t stream)
{
    char* ws = (char*)d_ws;

    // ---- canonical bf16 tensor area (element offsets) ----
    static const int   CN[14] = {1572864, 1572864, 1769472, 1769472, 589824, 589824,
                                 2359296, 2359296, 196608, 2304, 768, 3072, 3072, 128};
    static const size_t COFF[14] = {0, 1572864, 3145728, 4915200, 6684672, 7274496,
                                    7864320, 10223616, 12582912, 12779520, 12781824,
                                    12782592, 12785664, 12788736};
    // canon slots: 0 treeF(d_in 0), 1 featF(1), 2 W_iou(2), 3 U_iou(4), 4 W_f(5),
    //              5 U_f(7), 6 W_ih(8), 7 W_hh(10), 8 W_cls(12), 9 b_iou(3),
    //              10 b_f(6), 11 b_ih(9), 12 b_hh(11), 13 b_cls(13)
    static const int SRCI[14] = {0, 1, 2, 4, 5, 7, 8, 10, 12, 3, 6, 9, 11, 13};

    uint16_t* canon = (uint16_t*)ws;
    const uint16_t* treeF = canon + COFF[0];
    const uint16_t* featF = canon + COFF[1];
    const uint16_t* W_iou = canon + COFF[2];
    const uint16_t* U_iou = canon + COFF[3];
    const uint16_t* W_f   = canon + COFF[4];
    const uint16_t* U_f   = canon + COFF[5];
    const uint16_t* W_ih  = canon + COFF[6];
    const uint16_t* W_hh  = canon + COFF[7];
    const uint16_t* W_cls = canon + COFF[8];
    const uint16_t* b_iou = canon + COFF[9];
    const uint16_t* b_f   = canon + COFF[10];
    const uint16_t* b_ih  = canon + COFF[11];
    const uint16_t* b_hh  = canon + COFF[12];
    const uint16_t* b_cls = canon + COFF[13];

    const size_t CANON_B = 25577728;                  // 12788864 el * 2
    uint16_t* x_iou   = (uint16_t*)(ws + CANON_B);            //  9437184 B
    uint16_t* seq_pre = (uint16_t*)(ws + CANON_B + 9437184);  // 12582912 B
    uint16_t* x_f     = (uint16_t*)(ws + CANON_B + 22020096); //  3145728 B
    uint16_t* fdot    = (uint16_t*)(ws + CANON_B + 25165824); //  3145728 B
    uint16_t* tree_hb = (uint16_t*)(ws + CANON_B + 28311552); //  3147264 B (2049 rows)
    float*    tree_c  = (float*)   (ws + CANON_B + 31458816); //  6291456 B
    uint16_t* hs_b    = (uint16_t*)(ws + CANON_B + 37750272); //  3145728 B
    float*    logits  = (float*)   (ws + CANON_B + 40896000); //  1048576 B
    u64*      h_comm  = (u64*)     (ws + CANON_B + 41944576); //    12288 B (2x384 u64 used)
    int*      mode    = (int*)     (ws + CANON_B + 41956864); //      256 B
    int*      ctl     = mode + 16;                            // ctl[0]=ticket, ctl[1]=target
    const size_t WS_NEEDED = CANON_B + 41957120;              // ~64.4 MB
    if (ws_size < WS_NEEDED) return;  // diagnostic: out stays 0 (absmax ~8.56)

    hipMemsetAsync(h_comm, 0, 12288 + 256, stream);   // tags + mode + ctl
    hipMemsetAsync(ctl + 1, 0xFF, 4, stream);         // target XCC = -1
    hipMemsetAsync(tree_hb + (size_t)2048 * 768, 0, 1536, stream);  // phantom row

    detect_mode<<<256, 256, 0, stream>>>((const uint16_t*)d_in[0], mode);

    ConvArgs ca;
    for (int i = 0; i < 14; ++i) {
        ca.src[i] = d_in[SRCI[i]];
        ca.dst[i] = canon + COFF[i];
        ca.n[i]   = CN[i];
    }
    conv_canon<<<dim3(1152, 14), 256, 0, stream>>>(ca, mode);

    gemm_pre<<<dim3(96, 128), 256, 0, stream>>>(treeF, featF, W_iou, b_iou, W_f, b_f,
                                                W_ih, b_ih, b_hh, x_iou, x_f, seq_pre);

    // level 0 (leaves 1024..2047): combine only
    tree_combine<<<1024 * 3, 256, 0, stream>>>(1024, 1024, x_iou, fdot, tree_hb, tree_c);
    for (int lvl = 1; lvl <= 11; ++lvl) {
        int s = (lvl == 11) ? 0 : (1 << (10 - lvl));
        int m = (lvl == 11) ? 1 : (1 << (10 - lvl));
        int mt1 = (m + 15) >> 4, mt2 = (2 * m + 15) >> 4;
        int tiles = mt1 * 144 + mt2 * 48;
        tree_dots_mfma<<<(tiles + 3) / 4, 256, 0, stream>>>(s, m, U_iou, U_f, x_f,
                                                            x_iou, fdot, tree_hb);
        tree_combine<<<m * 3, 256, 0, stream>>>(s, m, x_iou, fdot, tree_hb, tree_c);
    }

    seq_lstm<<<SEQ_LAUNCH, 512, 0, stream>>>(W_hh, seq_pre, hs_b, h_comm, ctl);

    cls_mfma<<<256, 256, 0, stream>>>(tree_hb, hs_b, W_cls, b_cls, logits);
    col_softmax<<<128, 256, 0, stream>>>(logits, d_out, mode);
}

// Round 10
// 3652.063 us; speedup vs baseline: 1.2719x; 1.2719x over previous
//
#include <hip/hip_runtime.h>
#include <stdint.h>

// ---------------------------------------------------------------------------
// TreeLSTMParser: N=2048 nodes/timesteps, D_IN=H=768, OUT=128.
// Tree: complete binary tree, parent(i)=(i-1)/2; level L = [2^(10-L),2^(11-L))
// for L=1..10, level 0 = leaves [1024,2048), level 11 = {0}.
//
// Inputs fp32 (detector-confirmed r3).  All tensors canonicalized to bf16.
//
// v13b: v13 with the asm pin fixed (per-component "+v" on .x/.y/.z/.w —
// 128-bit tied uint4 constraint is unsupported: "tied indirect register").
// r14 post-mortem of v12 (3100->4690us): wq[24]=96 VGPR > budget; VGPR=72 +
// WRITE 15.4MB = scratch spill; occupancy halved.  Residency evidence:
// uint4 wq[12] (v4) -> VGPR=64 RESIDENT; bf16x8 wq[12] (v8/v11) -> VGPR=44
// NOT resident (L2 re-read each step, hidden by 16-wave TLP); >48 weight
// VGPRs -> spill.  v13: uint4 wq[12] + component asm pin + bit_cast at MFMA
// use; 12 MFMA in 3 independent 4-deep chains.  All else = v11 (3573us).
// ---------------------------------------------------------------------------

typedef __bf16 bf16x8 __attribute__((ext_vector_type(8)));
typedef float  f32x4  __attribute__((ext_vector_type(4)));
typedef unsigned long long u64;

__device__ __forceinline__ float bf2f(uint16_t v) {
    return __uint_as_float(((uint32_t)v) << 16);
}
__device__ __forceinline__ uint16_t f2bf(float f) {
    uint32_t u = __float_as_uint(f);
    uint32_t r = (u + 0x7fffu + ((u >> 16) & 1u)) >> 16;
    return (uint16_t)r;
}
__device__ __forceinline__ float sigf(float x) { return 1.0f / (1.0f + __expf(-x)); }
__device__ __forceinline__ float tanh_f(float x) {
    x = fminf(fmaxf(x, -15.0f), 15.0f);
    float e = __expf(2.0f * x);
    return (e - 1.0f) / (e + 1.0f);
}

// ---------------------------------------------------------------------------
// K0a: dtype detector (fp32 read as bf16 halfwords shows exponent==0xFF).
// ---------------------------------------------------------------------------
__global__ __launch_bounds__(256)
void detect_mode(const uint16_t* __restrict__ p, int* __restrict__ mode)
{
    int i = blockIdx.x * 256 + threadIdx.x;
    uint16_t v = p[i];
    bool bad = ((v >> 7) & 0xFF) == 0xFF;
    if (__ballot(bad) != 0ull) {
        if ((threadIdx.x & 63) == 0) atomicOr(mode, 1);
    }
}

// ---------------------------------------------------------------------------
// K0b: canonicalize all tensors to bf16 (copy or downcast per mode).
// ---------------------------------------------------------------------------
struct ConvArgs {
    const void* src[14];
    void*       dst[14];
    int         n[14];
};

__global__ __launch_bounds__(256)
void conv_canon(ConvArgs a, const int* __restrict__ mode)
{
    int t = blockIdx.y;
    int n = a.n[t];
    int i = (blockIdx.x * 256 + threadIdx.x) * 8;
    if (i >= n) return;
    uint16_t* d = (uint16_t*)a.dst[t] + i;
    if (*mode) {
        const float* s = (const float*)a.src[t] + i;
        float4 v0 = reinterpret_cast<const float4*>(s)[0];
        float4 v1 = reinterpret_cast<const float4*>(s)[1];
        d[0] = f2bf(v0.x); d[1] = f2bf(v0.y); d[2] = f2bf(v0.z); d[3] = f2bf(v0.w);
        d[4] = f2bf(v1.x); d[5] = f2bf(v1.y); d[6] = f2bf(v1.z); d[7] = f2bf(v1.w);
    } else {
        *reinterpret_cast<uint4*>(d) =
            *reinterpret_cast<const uint4*>((const uint16_t*)a.src[t] + i);
    }
}

// ---------------------------------------------------------------------------
// K1: fused projection GEMM.  C(2048 x 6144) = A @ W^T + bias, K=768.
// seq region written PERMUTED for 32-wide wg ownership (24 wgs x 32 j,
// v4 mapping): idx = (j>>5)*128 + g*32 + (j&31)
// ---------------------------------------------------------------------------
__global__ __launch_bounds__(256)
void gemm_pre(const uint16_t* __restrict__ treeF, const uint16_t* __restrict__ featF,
              const uint16_t* __restrict__ W_iou, const uint16_t* __restrict__ b_iou,
              const uint16_t* __restrict__ W_f,   const uint16_t* __restrict__ b_f,
              const uint16_t* __restrict__ W_ih,  const uint16_t* __restrict__ b_ih,
              const uint16_t* __restrict__ b_hh,
              uint16_t* __restrict__ x_iou, uint16_t* __restrict__ x_f,
              uint16_t* __restrict__ seq_pre)
{
    int lane = threadIdx.x & 63;
    int wave = threadIdx.x >> 6;
    int colTile = blockIdx.x * 4 + wave;     // 0..383
    int row0 = blockIdx.y * 16;              // 0..2032
    int cl = lane & 15, quad = lane >> 4;
    int colg = colTile * 16;

    const uint16_t* A; const uint16_t* W; int wrow;
    if (colTile < 144)      { A = treeF; W = W_iou; wrow = colg; }
    else if (colTile < 192) { A = treeF; W = W_f;   wrow = colg - 2304; }
    else                    { A = featF; W = W_ih;  wrow = colg - 3072; }

    const uint16_t* arow = A + (size_t)(row0 + cl) * 768 + quad * 8;
    const uint16_t* brow = W + (size_t)(wrow + cl) * 768 + quad * 8;

    f32x4 acc = {0.f, 0.f, 0.f, 0.f};
    for (int k = 0; k < 768; k += 32) {
        bf16x8 a = *reinterpret_cast<const bf16x8*>(arow + k);
        bf16x8 b = *reinterpret_cast<const bf16x8*>(brow + k);
        acc = __builtin_amdgcn_mfma_f32_16x16x32_bf16(a, b, acc, 0, 0, 0);
    }

    // C/D layout: col = lane&15, row = quad*4 + reg   [m89-verified]
    int outcol = colg + cl;
    float bias; uint16_t* dst; int ldc; int ccol;
    if (colTile < 144)      { bias = bf2f(b_iou[outcol]); dst = x_iou; ldc = 2304; ccol = outcol; }
    else if (colTile < 192) { int c = outcol - 2304; bias = bf2f(b_f[c]); dst = x_f; ldc = 768;  ccol = c; }
    else {
        int c = outcol - 3072;               // c = g*768 + j
        int g = c / 768, j = c - g * 768;
        bias = bf2f(b_ih[c]) + bf2f(b_hh[c]);
        dst = seq_pre; ldc = 3072;
        ccol = (j >> 5) * 128 + g * 32 + (j & 31);   // v4 permutation
    }
    for (int r = 0; r < 4; ++r) {
        int row = row0 + quad * 4 + r;
        dst[(size_t)row * ldc + ccol] = f2bf(acc[r] + bias);
    }
}

// ---------------------------------------------------------------------------
// K2a v2: per-level dot products (tree), MFMA.
// GEMM1: x_iou[p][j] += dot(U_iou[j], h[2p+1]+h[2p+2]), p-tile 16 x j-tile 16,
//        hsum via two chained MFMAs.  144 col tiles.
// GEMM2: fdot[c][j] = x_f[parent(c)][j] + dot(U_f[j], h[c]).  48 col tiles.
// hb row 2048 = zeros (node 1023 phantom child).  Row-clamp + store-guard
// handle partial tiles (m<16).
// ---------------------------------------------------------------------------
__global__ __launch_bounds__(256)
void tree_dots_mfma(int s, int m,
                    const uint16_t* __restrict__ U_iou, const uint16_t* __restrict__ U_f,
                    const uint16_t* __restrict__ x_f,
                    uint16_t* __restrict__ x_iou, uint16_t* __restrict__ fdot,
                    const uint16_t* __restrict__ hb)
{
    int lane = threadIdx.x & 63;
    int wave = threadIdx.x >> 6;
    int cl = lane & 15, quad = lane >> 4;
    int mt1 = (m + 15) >> 4;
    int mt2 = (2 * m + 15) >> 4;
    int t1 = mt1 * 144;
    int tile = blockIdx.x * 4 + wave;
    if (tile >= t1 + mt2 * 48) return;

    if (tile < t1) {
        int rt = tile / 144, ct = tile - rt * 144;
        int pl = rt * 16 + cl; if (pl > m - 1) pl = m - 1;   // A-row clamp
        int p = s + pl;
        const uint16_t* a1 = hb + (size_t)(2 * p + 1) * 768 + quad * 8;
        const uint16_t* a2 = hb + (size_t)(2 * p + 2) * 768 + quad * 8;
        const uint16_t* brow = U_iou + (size_t)(ct * 16 + cl) * 768 + quad * 8;
        f32x4 acc = {0.f, 0.f, 0.f, 0.f};
        for (int k = 0; k < 768; k += 32) {
            bf16x8 b = *reinterpret_cast<const bf16x8*>(brow + k);
            acc = __builtin_amdgcn_mfma_f32_16x16x32_bf16(
                      *reinterpret_cast<const bf16x8*>(a1 + k), b, acc, 0, 0, 0);
            acc = __builtin_amdgcn_mfma_f32_16x16x32_bf16(
                      *reinterpret_cast<const bf16x8*>(a2 + k), b, acc, 0, 0, 0);
        }
        int outcol = ct * 16 + cl;
        #pragma unroll
        for (int r = 0; r < 4; ++r) {
            int prow = rt * 16 + quad * 4 + r;
            if (prow < m) {
                size_t off = (size_t)(s + prow) * 2304 + outcol;
                x_iou[off] = f2bf(bf2f(x_iou[off]) + acc[r]);
            }
        }
    } else {
        int t2i = tile - t1;
        int rt = t2i / 48, ct = t2i - rt * 48;
        int c0 = 2 * s + 1;
        int rl = rt * 16 + cl; if (rl > 2 * m - 1) rl = 2 * m - 1;  // clamp
        const uint16_t* a = hb + (size_t)(c0 + rl) * 768 + quad * 8;
        const uint16_t* brow = U_f + (size_t)(ct * 16 + cl) * 768 + quad * 8;
        f32x4 acc = {0.f, 0.f, 0.f, 0.f};
        for (int k = 0; k < 768; k += 32) {
            acc = __builtin_amdgcn_mfma_f32_16x16x32_bf16(
                      *reinterpret_cast<const bf16x8*>(a + k),
                      *reinterpret_cast<const bf16x8*>(brow + k), acc, 0, 0, 0);
        }
        int outcol = ct * 16 + cl;
        #pragma unroll
        for (int r = 0; r < 4; ++r) {
            int rr = rt * 16 + quad * 4 + r;
            int c = c0 + rr;
            if (rr < 2 * m && c < 2048) {
                int p = (c - 1) >> 1;
                fdot[(size_t)c * 768 + outcol] =
                    f2bf(bf2f(x_f[(size_t)p * 768 + outcol]) + acc[r]);
            }
        }
    }
}

// ---------------------------------------------------------------------------
// K2b: per-level combine (tree).  Writes bf16 h (tree_hb) + fp32 c.
// ---------------------------------------------------------------------------
__global__ __launch_bounds__(256)
void tree_combine(int s, int m, const uint16_t* __restrict__ x_iou,
                  const uint16_t* __restrict__ fdot,
                  uint16_t* __restrict__ tree_hb, float* __restrict__ tree_c)
{
    int id = blockIdx.x * 256 + threadIdx.x;
    int pl = id / 768;
    int j = id - pl * 768;
    int p = s + pl;
    const uint16_t* iou = x_iou + (size_t)p * 2304;
    float iv = sigf(bf2f(iou[j]));
    float ov = sigf(bf2f(iou[768 + j]));
    float uv = tanh_f(bf2f(iou[1536 + j]));
    float csum = 0.f;
    int c1 = 2 * p + 1, c2 = 2 * p + 2;
    if (c1 < 2048) csum += sigf(bf2f(fdot[(size_t)c1 * 768 + j])) * tree_c[(size_t)c1 * 768 + j];
    if (c2 < 2048) csum += sigf(bf2f(fdot[(size_t)c2 * 768 + j])) * tree_c[(size_t)c2 * 768 + j];
    float c = iv * uv + csum;
    tree_c[(size_t)p * 768 + j] = c;
    tree_hb[(size_t)p * 768 + j] = f2bf(ov * tanh_f(c));
}

// ---------------------------------------------------------------------------
// K3 v13b: persistent sequential LSTM.  Launch 256 wgs x 1024 thr; 24 workers
// claim slots on ONE XCD (v10 protocol).  v11 structure; weights PINNED:
// uint4 wq[12] + per-component asm pin (non-rematerializable defs) +
// bit_cast to bf16x8 at MFMA use.  12 MFMA in 3 independent 4-deep chains.
//
// h_comm: 2 parity buffers x 384 u64; word w covers j = {2w, 2w+1}:
//   wd = (tag=t+1)<<32 | bf16(h[2w+1])<<16 | bf16(h[2w]).
// ---------------------------------------------------------------------------
#define SEQ_WGS 24
#define SEQ_LAUNCH 256
__global__ __launch_bounds__(1024)
void seq_lstm(const uint16_t* __restrict__ W_hh, const uint16_t* __restrict__ seq_pre,
              uint16_t* __restrict__ hsb, u64* __restrict__ h_comm, int* __restrict__ ctl)
{
    __shared__ uint16_t hb16[2][768];   // bf16 h, parity-buffered
    __shared__ float    part[2][128];   // [khalf][local row = g*32 + jl]
    __shared__ int      s_slot;

    int tid = threadIdx.x;

    // ---- placement claim: prefer one XCD for all workers ----
    int xcc;
    asm("s_getreg_b32 %0, hwreg(HW_REG_XCC_ID)" : "=s"(xcc));
    if (tid == 0) {
        int tgt = atomicCAS(&ctl[1], -1, xcc);   // first claimer sets target
        if (tgt == -1) tgt = xcc;
        int slot;
        if (xcc == tgt) {
            slot = atomicAdd(&ctl[0], 1);
        } else {
            int it = 0;
            for (;;) {
                int tk = __hip_atomic_load(&ctl[0], __ATOMIC_RELAXED,
                                           __HIP_MEMORY_SCOPE_AGENT);
                if (tk >= SEQ_WGS) { slot = 0x7fffffff; break; }  // filled: exit
                if (++it > 2000) { slot = atomicAdd(&ctl[0], 1); break; }  // fallback
                __builtin_amdgcn_s_sleep(8);
            }
        }
        s_slot = slot;
    }
    __syncthreads();
    int bid = s_slot;               // worker slot 0..23
    if (bid >= SEQ_WGS) return;     // non-worker wgs exit whole

    int lane = tid & 63;
    int w    = tid >> 6;            // wave 0..15
    int tile = w >> 1;              // 0..7  (16 local W-rows each)
    int khalf = w & 1;              // K half: 0 -> [0,384), 1 -> [384,768)
    int tg = tile >> 1;                         // gate of this tile
    int tj = (tile & 1) * 16 + (lane & 15);     // jl of this lane's W row
    int rglob = tg * 768 + bid * 32 + tj;       // global W_hh row

    // weight fragments (uint4, component-pinned resident): lane l holds
    // W[rglob][khalf*384 + ks*32 + (l>>4)*8 ..+8)
    uint4 wq[12];
    {
        const uint16_t* src = W_hh + (size_t)rglob * 768 + khalf * 384 + (lane >> 4) * 8;
        #pragma unroll
        for (int i = 0; i < 12; ++i)
            wq[i] = *reinterpret_cast<const uint4*>(src + i * 32);
        #pragma unroll
        for (int i = 0; i < 12; ++i)
            asm volatile("" : "+v"(wq[i].x), "+v"(wq[i].y),
                              "+v"(wq[i].z), "+v"(wq[i].w));
    }

    float cstate = 0.f;             // live in threads 0..31 (jl = tid)

    for (int t = 0; t < 2048; ++t) {
        // gate-thread prefetch of seq_pre (4 gates, issued before the poll)
        float p0 = 0.f, p1 = 0.f, p2 = 0.f, p3 = 0.f;
        if (tid < 32) {
            const uint16_t* sp = seq_pre + (size_t)t * 3072 + bid * 128 + tid;
            p0 = bf2f(sp[0]);  p1 = bf2f(sp[32]);
            p2 = bf2f(sp[64]); p3 = bf2f(sp[96]);
        }

        uint16_t* hb = hb16[t & 1];
        if (t > 0) {
            if (tid < 384) {
                const u64* hw = h_comm + (size_t)((t - 1) & 1) * 384 + tid;
                u64 a;
                int guard = 0;
                for (;;) {
                    a = __hip_atomic_load(hw, __ATOMIC_RELAXED,
                                          __HIP_MEMORY_SCOPE_AGENT);
                    if ((uint32_t)(a >> 32) >= (uint32_t)t) break;
                    if (++guard > (1 << 22)) break;      // hang bailout
                    __builtin_amdgcn_s_sleep(1);
                }
                hb[2 * tid]     = (uint16_t)a;           // bf16 payload lo
                hb[2 * tid + 1] = (uint16_t)(a >> 16);   // bf16 payload hi
            }
        } else {
            if (tid < 768) hb[tid] = 0;
        }
        __syncthreads();   // B1

        // matvec tile: 12 MFMA in 3 independent 4-deep chains,
        // X = h broadcast, Y = 16 W rows
        {
            const uint16_t* hbase = hb + khalf * 384 + (lane >> 4) * 8;
            f32x4 ac0 = {0.f,0.f,0.f,0.f}, ac1 = {0.f,0.f,0.f,0.f}, ac2 = {0.f,0.f,0.f,0.f};
            #pragma unroll
            for (int ks = 0; ks < 4; ++ks) {
                ac0 = __builtin_amdgcn_mfma_f32_16x16x32_bf16(
                          *reinterpret_cast<const bf16x8*>(hbase + ks * 32),
                          __builtin_bit_cast(bf16x8, wq[ks]), ac0, 0, 0, 0);
                ac1 = __builtin_amdgcn_mfma_f32_16x16x32_bf16(
                          *reinterpret_cast<const bf16x8*>(hbase + (ks + 4) * 32),
                          __builtin_bit_cast(bf16x8, wq[ks + 4]), ac1, 0, 0, 0);
                ac2 = __builtin_amdgcn_mfma_f32_16x16x32_bf16(
                          *reinterpret_cast<const bf16x8*>(hbase + (ks + 8) * 32),
                          __builtin_bit_cast(bf16x8, wq[ks + 8]), ac2, 0, 0, 0);
            }
            if ((lane >> 4) == 0)
                part[khalf][tile * 16 + lane] = ac0[0] + ac1[0] + ac2[0];
        }
        __syncthreads();   // B2

        if (tid < 32) {
            int jl = tid;
            float gi = part[0][jl]      + part[1][jl]      + p0;
            float gf = part[0][32 + jl] + part[1][32 + jl] + p1;
            float gg = part[0][64 + jl] + part[1][64 + jl] + p2;
            float go = part[0][96 + jl] + part[1][96 + jl] + p3;

            float iv = sigf(gi), fv = sigf(gf), gv = tanh_f(gg), ov = sigf(go);
            cstate = fv * cstate + iv * gv;
            float hv = ov * tanh_f(cstate);

            // pack 2 j per word; publisher = even jl's thread (q = jl>>1)
            uint32_t hb16v = (uint32_t)f2bf(hv);
            uint32_t hv_hi = __shfl(hb16v, 2 * (tid >> 1) + 1);  // odd partner
            uint32_t hv_lo = __shfl(hb16v, 2 * (tid >> 1));      // even partner
            if ((tid & 1) == 0) {
                int q = tid >> 1;                    // 0..15
                int wdx = bid * 16 + q;              // global word index
                u64 wd = ((u64)(uint32_t)(t + 1) << 32)
                       | ((u64)hv_hi << 16) | (u64)hv_lo;
                __hip_atomic_store(h_comm + (size_t)(t & 1) * 384 + wdx, wd,
                                   __ATOMIC_RELAXED, __HIP_MEMORY_SCOPE_AGENT);
            }
            int j = bid * 32 + jl;
            hsb[(size_t)t * 768 + j] = (uint16_t)hb16v;   // off critical path
        }
        // no trailing barrier: hb16 parity + barrier chain protect reuse
    }
}

// ---------------------------------------------------------------------------
// K4 v2: classifier via MFMA.  logits[n][o] = b_cls[o] +
//   dot(W_cls[o][0:768], tree_hb[n]) + dot(W_cls[o][768:1536], hs_b[n]).
// 128 row tiles x 8 col tiles = 1024 tiles, 4 waves/block -> 256 blocks.
// ---------------------------------------------------------------------------
__global__ __launch_bounds__(256)
void cls_mfma(const uint16_t* __restrict__ hbT, const uint16_t* __restrict__ hsb,
              const uint16_t* __restrict__ W_cls, const uint16_t* __restrict__ b_cls,
              float* __restrict__ logits)
{
    int lane = threadIdx.x & 63;
    int wave = threadIdx.x >> 6;
    int cl = lane & 15, quad = lane >> 4;
    int tile = blockIdx.x * 4 + wave;    // 0..1023
    int rt = tile >> 3, ct = tile & 7;
    const uint16_t* a1 = hbT + (size_t)(rt * 16 + cl) * 768 + quad * 8;
    const uint16_t* a2 = hsb + (size_t)(rt * 16 + cl) * 768 + quad * 8;
    const uint16_t* brow = W_cls + (size_t)(ct * 16 + cl) * 1536 + quad * 8;
    f32x4 acc = {0.f, 0.f, 0.f, 0.f};
    for (int k = 0; k < 768; k += 32) {
        acc = __builtin_amdgcn_mfma_f32_16x16x32_bf16(
                  *reinterpret_cast<const bf16x8*>(a1 + k),
                  *reinterpret_cast<const bf16x8*>(brow + k), acc, 0, 0, 0);
        acc = __builtin_amdgcn_mfma_f32_16x16x32_bf16(
                  *reinterpret_cast<const bf16x8*>(a2 + k),
                  *reinterpret_cast<const bf16x8*>(brow + 768 + k), acc, 0, 0, 0);
    }
    int outcol = ct * 16 + cl;
    float bias = bf2f(b_cls[outcol]);
    #pragma unroll
    for (int r = 0; r < 4; ++r) {
        int n = rt * 16 + quad * 4 + r;
        logits[(size_t)n * 128 + outcol] = acc[r] + bias;
    }
}

// ---------------------------------------------------------------------------
// K5: log_softmax over axis=0 per class column.  Output dtype per mode.
// ---------------------------------------------------------------------------
__global__ __launch_bounds__(256)
void col_softmax(const float* __restrict__ logits, void* __restrict__ out,
                 const int* __restrict__ mode)
{
    __shared__ float sred[256];
    int o = blockIdx.x, tid = threadIdx.x;
    float v[8];
    float mx = -1e30f;
    #pragma unroll
    for (int i = 0; i < 8; ++i) {
        v[i] = logits[(size_t)(i * 256 + tid) * 128 + o];
        mx = fmaxf(mx, v[i]);
    }
    sred[tid] = mx; __syncthreads();
    for (int s2 = 128; s2 > 0; s2 >>= 1) {
        if (tid < s2) sred[tid] = fmaxf(sred[tid], sred[tid + s2]);
        __syncthreads();
    }
    float M = sred[0]; __syncthreads();
    float sm = 0.f;
    #pragma unroll
    for (int i = 0; i < 8; ++i) sm += __expf(v[i] - M);
    sred[tid] = sm; __syncthreads();
    for (int s2 = 128; s2 > 0; s2 >>= 1) {
        if (tid < s2) sred[tid] += sred[tid + s2];
        __syncthreads();
    }
    float lse = M + logf(sred[0]);
    bool fp32 = (*mode != 0);
    #pragma unroll
    for (int i = 0; i < 8; ++i) {
        size_t idx = (size_t)(i * 256 + tid) * 128 + o;
        float val = v[i] - lse;
        if (fp32) ((float*)out)[idx] = val;
        else      ((uint16_t*)out)[idx] = f2bf(val);
    }
}

// ---------------------------------------------------------------------------
extern "C" void kernel_launch(void* const* d_in, const int* in_sizes, int n_in,
                              void* d_out, int out_size, void* d_ws, size_t ws_size,
                              hipStream_t stream)
{
    char* ws = (char*)d_ws;

    // ---- canonical bf16 tensor area (element offsets) ----
    static const int   CN[14] = {1572864, 1572864, 1769472, 1769472, 589824, 589824,
                                 2359296, 2359296, 196608, 2304, 768, 3072, 3072, 128};
    static const size_t COFF[14] = {0, 1572864, 3145728, 4915200, 6684672, 7274496,
                                    7864320, 10223616, 12582912, 12779520, 12781824,
                                    12782592, 12785664, 12788736};
    // canon slots: 0 treeF(d_in 0), 1 featF(1), 2 W_iou(2), 3 U_iou(4), 4 W_f(5),
    //              5 U_f(7), 6 W_ih(8), 7 W_hh(10), 8 W_cls(12), 9 b_iou(3),
    //              10 b_f(6), 11 b_ih(9), 12 b_hh(11), 13 b_cls(13)
    static const int SRCI[14] = {0, 1, 2, 4, 5, 7, 8, 10, 12, 3, 6, 9, 11, 13};

    uint16_t* canon = (uint16_t*)ws;
    const uint16_t* treeF = canon + COFF[0];
    const uint16_t* featF = canon + COFF[1];
    const uint16_t* W_iou = canon + COFF[2];
    const uint16_t* U_iou = canon + COFF[3];
    const uint16_t* W_f   = canon + COFF[4];
    const uint16_t* U_f   = canon + COFF[5];
    const uint16_t* W_ih  = canon + COFF[6];
    const uint16_t* W_hh  = canon + COFF[7];
    const uint16_t* W_cls = canon + COFF[8];
    const uint16_t* b_iou = canon + COFF[9];
    const uint16_t* b_f   = canon + COFF[10];
    const uint16_t* b_ih  = canon + COFF[11];
    const uint16_t* b_hh  = canon + COFF[12];
    const uint16_t* b_cls = canon + COFF[13];

    const size_t CANON_B = 25577728;                  // 12788864 el * 2
    uint16_t* x_iou   = (uint16_t*)(ws + CANON_B);            //  9437184 B
    uint16_t* seq_pre = (uint16_t*)(ws + CANON_B + 9437184);  // 12582912 B
    uint16_t* x_f     = (uint16_t*)(ws + CANON_B + 22020096); //  3145728 B
    uint16_t* fdot    = (uint16_t*)(ws + CANON_B + 25165824); //  3145728 B
    uint16_t* tree_hb = (uint16_t*)(ws + CANON_B + 28311552); //  3147264 B (2049 rows)
    float*    tree_c  = (float*)   (ws + CANON_B + 31458816); //  6291456 B
    uint16_t* hs_b    = (uint16_t*)(ws + CANON_B + 37750272); //  3145728 B
    float*    logits  = (float*)   (ws + CANON_B + 40896000); //  1048576 B
    u64*      h_comm  = (u64*)     (ws + CANON_B + 41944576); //    12288 B (2x384 u64 used)
    int*      mode    = (int*)     (ws + CANON_B + 41956864); //      256 B
    int*      ctl     = mode + 16;                            // ctl[0]=ticket, ctl[1]=target
    const size_t WS_NEEDED = CANON_B + 41957120;              // ~64.4 MB
    if (ws_size < WS_NEEDED) return;  // diagnostic: out stays 0 (absmax ~8.56)

    (void)hipMemsetAsync(h_comm, 0, 12288 + 256, stream);   // tags + mode + ctl
    (void)hipMemsetAsync(ctl + 1, 0xFF, 4, stream);         // target XCC = -1
    (void)hipMemsetAsync(tree_hb + (size_t)2048 * 768, 0, 1536, stream);  // phantom row

    detect_mode<<<256, 256, 0, stream>>>((const uint16_t*)d_in[0], mode);

    ConvArgs ca;
    for (int i = 0; i < 14; ++i) {
        ca.src[i] = d_in[SRCI[i]];
        ca.dst[i] = canon + COFF[i];
        ca.n[i]   = CN[i];
    }
    conv_canon<<<dim3(1152, 14), 256, 0, stream>>>(ca, mode);

    gemm_pre<<<dim3(96, 128), 256, 0, stream>>>(treeF, featF, W_iou, b_iou, W_f, b_f,
                                                W_ih, b_ih, b_hh, x_iou, x_f, seq_pre);

    // level 0 (leaves 1024..2047): combine only
    tree_combine<<<1024 * 3, 256, 0, stream>>>(1024, 1024, x_iou, fdot, tree_hb, tree_c);
    for (int lvl = 1; lvl <= 11; ++lvl) {
        int s = (lvl == 11) ? 0 : (1 << (10 - lvl));
        int m = (lvl == 11) ? 1 : (1 << (10 - lvl));
        int mt1 = (m + 15) >> 4, mt2 = (2 * m + 15) >> 4;
        int tiles = mt1 * 144 + mt2 * 48;
        tree_dots_mfma<<<(tiles + 3) / 4, 256, 0, stream>>>(s, m, U_iou, U_f, x_f,
                                                            x_iou, fdot, tree_hb);
        tree_combine<<<m * 3, 256, 0, stream>>>(s, m, x_iou, fdot, tree_hb, tree_c);
    }

    seq_lstm<<<SEQ_LAUNCH, 1024, 0, stream>>>(W_hh, seq_pre, hs_b, h_comm, ctl);

    cls_mfma<<<256, 256, 0, stream>>>(tree_hb, hs_b, W_cls, b_cls, logits);
    col_softmax<<<128, 256, 0, stream>>>(logits, d_out, mode);
}